// Round 1
// baseline (589.573 us; speedup 1.0000x reference)
//
#include <hip/hip_runtime.h>

#define DB 4
#define SS 4096
#define DD 1024
#define HH 16
#define HD 64
#define WW 128
#define NW 32
#define NG 32

typedef __bf16 bf16_t;
typedef bf16_t bf16x4 __attribute__((ext_vector_type(4)));
typedef bf16_t bf16x8 __attribute__((ext_vector_type(8)));
typedef float f32x4 __attribute__((ext_vector_type(4)));

typedef const __attribute__((address_space(1))) void* gptr_t;
typedef __attribute__((address_space(3))) void* lptr_t;

static __device__ __forceinline__ f32x4 mfma16(bf16x8 a, bf16x8 b, f32x4 c) {
    return __builtin_amdgcn_mfma_f32_16x16x32_bf16(a, b, c, 0, 0, 0);
}

// ---------------- dtype probe (1 = buffers are bf16, 0 = f32) ----------------
__global__ void detect_dtype(const unsigned short* __restrict__ q, int* __restrict__ flag) {
    int lane = threadIdx.x;  // 64 threads
    unsigned short u = q[2 * lane];
    bf16_t b;
    __builtin_memcpy(&b, &u, 2);
    float v = fabsf((float)b);
    bool ok = (v > 1e-5f) && (v < 1e5f);
    unsigned long long m = __ballot(ok);
    if (lane == 0) *flag = (__popcll(m) >= 32) ? 1 : 0;
}

// ---------------- conversions ----------------
__global__ void cvt_x(const void* __restrict__ src, bf16_t* __restrict__ dst,
                      const int* __restrict__ flag) {
    int i = blockIdx.x * blockDim.x + threadIdx.x;  // one per 4 elems, 4M threads
    int e = i * 4;
    if (*flag) {
        *(ushort4*)(dst + e) = ((const ushort4*)src)[i];
    } else {
        float4 f = ((const float4*)src)[i];
        bf16x4 o = { (bf16_t)f.x, (bf16_t)f.y, (bf16_t)f.z, (bf16_t)f.w };
        *(bf16x4*)(dst + e) = o;
    }
}

// W' interleaved layout for the K'-doubled GEMM:
//   W'[n][2*k0 + j]      = Wh[n][k0 + j]   (k0 mult of 32, j in [0,32))
//   W'[n][2*k0 + 32 + j] = Wl[n][k0 + j]
// so K'-block 2t pairs X k-block t with Wh, block 2t+1 pairs the SAME X block with Wl.
__global__ void cvt_w(const void* __restrict__ src, bf16_t* __restrict__ wp,
                      const int* __restrict__ flag) {
    int i = blockIdx.x * blockDim.x + threadIdx.x;  // one per 4 src elems, 256K threads
    int e = i * 4;
    int n = e >> 10, k = e & 1023;
    int dst = n * 2048 + ((k >> 5) << 6) + (k & 31);
    if (*flag) {
        *(ushort4*)(wp + dst) = ((const ushort4*)src)[i];
        ushort4 z = {0, 0, 0, 0};
        *(ushort4*)(wp + dst + 32) = z;
    } else {
        float4 f = ((const float4*)src)[i];
        bf16x4 h = { (bf16_t)f.x, (bf16_t)f.y, (bf16_t)f.z, (bf16_t)f.w };
        bf16x4 l = { (bf16_t)(f.x - (float)h[0]), (bf16_t)(f.y - (float)h[1]),
                     (bf16_t)(f.z - (float)h[2]), (bf16_t)(f.w - (float)h[3]) };
        *(bf16x4*)(wp + dst) = h;
        *(bf16x4*)(wp + dst + 32) = l;
    }
}

__global__ void cvt_bias(const void* b0, const void* b1, const void* b2, const void* b3,
                         float* __restrict__ dst, const int* __restrict__ flag) {
    int i = blockIdx.x * blockDim.x + threadIdx.x;  // 4096
    const void* s = (i >> 10) == 0 ? b0 : (i >> 10) == 1 ? b1 : (i >> 10) == 2 ? b2 : b3;
    int j = i & 1023;
    dst[i] = (*flag) ? (float)((const bf16_t*)s)[j] : ((const float*)s)[j];
}

__global__ void expand_out(const bf16_t* __restrict__ src, void* __restrict__ dst,
                           const int* __restrict__ flag) {
    int i = blockIdx.x * blockDim.x + threadIdx.x;  // one per 4 elems
    int e = i * 4;
    ushort4 u = *(const ushort4*)(src + e);
    if (*flag) {
        ((ushort4*)dst)[i] = u;
    } else {
        const bf16x4 b = *(const bf16x4*)&u;
        float4 f = { (float)b[0], (float)b[1], (float)b[2], (float)b[3] };
        ((float4*)dst)[i] = f;
    }
}

// ---------------- 8-phase 256x256 GEMM (T2+T3+T4+T5), K'=2048 interleaved ----------------
// Y[m][n] = sum_k' X'[m][k']*W'[n][k'] + bias[n], where X' duplicates each 32-k block
// (done at staging via per-lane global src addr; LDS dest stays linear per gload_lds rule).
// 512 thr = 8 waves (2Mx4N), tile 256x256, BK=64, LDS 128KB (2 dbuf x (A 32K + B 32K)).
// LDS row = 64 elems = 128B, XOR-swizzle byte ^= (row&7)<<4 (Guideline 4, both-sides).
// LDS A row order: [msub][wi][64] ; B row order: [nsub][wj][32]  (chunks contiguous).
// Chunk stage order per tile: Ac0(msub0), Bc0(nsub0), Ac1, Bc1 -> 2 gload_lds each.
// Wait ledger (derived, never drains in steady loop):
//   end-ph1 vmcnt(2): forces Ac1(t),Bc1(t) done (needed ph2/ph3); leaves Ac0(t+1) in flight
//   end-ph4 vmcnt(4): forces Ac0(t+1),Bc0(t+1) done (needed ph1); leaves Ac1,Bc1 in flight
// WAR safe: all buf-P ds_reads complete by end-ph3 barrier; P restaged at (t+1).ph1.
#define GFENCE() asm volatile("" ::: "memory")
#define MIDBAR() do { GFENCE(); __builtin_amdgcn_s_barrier(); GFENCE(); } while (0)
#define ENDBAR(N) do { asm volatile("s_waitcnt vmcnt(" #N ")" ::: "memory"); \
                       __builtin_amdgcn_s_barrier(); GFENCE(); } while (0)

#define QUAD_MFMA(MS, NS, BB)                                                          \
    do {                                                                               \
        __builtin_amdgcn_s_setprio(1);                                                 \
        _Pragma("unroll")                                                              \
        for (int t_ = 0; t_ < 4; ++t_) {                                               \
            _Pragma("unroll")                                                          \
            for (int u_ = 0; u_ < 2; ++u_) {                                           \
                acc[(MS)*4 + t_][(NS)*2 + u_] =                                        \
                    mfma16(a[t_][0], BB[u_][0], acc[(MS)*4 + t_][(NS)*2 + u_]);        \
                acc[(MS)*4 + t_][(NS)*2 + u_] =                                        \
                    mfma16(a[t_][1], BB[u_][1], acc[(MS)*4 + t_][(NS)*2 + u_]);        \
            }                                                                          \
        }                                                                              \
        __builtin_amdgcn_s_setprio(0);                                                 \
    } while (0)

__global__ __launch_bounds__(512, 2) void gemm8(const bf16_t* __restrict__ X,
                                                const bf16_t* __restrict__ Wp,
                                                const float* __restrict__ bias,
                                                bf16_t* __restrict__ Y) {
    __shared__ alignas(16) bf16_t sA[2][16384];   // 2 x 32KB
    __shared__ alignas(16) bf16_t sB[2][16384];   // 2 x 32KB

    const int tid  = threadIdx.x;
    const int lane = tid & 63;
    const int wv   = tid >> 6;
    const int c    = lane & 15;
    const int quad = lane >> 4;
    const int wi   = wv >> 2;   // 0..1 (M)
    const int wj   = wv & 3;    // 0..3 (N)

    // XCD-aware bijective swizzle (nwg=256, 8 XCDs)
    int wg = blockIdx.x;
    wg = (wg & 7) * 32 + (wg >> 3);
    const int mbase = (wg >> 2) * 256;
    const int nbase = (wg & 3) * 256;

    // ---- per-thread staging source base (chunk Ac0/Bc0, step e0, ktile 0) ----
    // dest within chunk: d = tid*16 -> srow in [0,64), scolS in [0,128)
    // inverse-swizzle the SOURCE so swizzled READS see linear data (involution).
    const int d0   = tid * 16;
    const int srow = d0 >> 7;
    const int scol = (d0 & 127) ^ ((srow & 7) << 4);
    const char* srcA = (const char*)X + (size_t)(mbase + srow) * 2048 + (scol & 63);
    const char* srcB = (const char*)Wp +
        (size_t)(nbase + ((srow >> 5) << 6) + (srow & 31)) * 4096 + scol;
    // constant deltas (derived from the lrow->grow inverses):
    //   A: +e*262144 (step), +chunk*131072 ; B: +e*524288, +chunk*131072
    char* const ldsA = (char*)&sA[0][0] + wv * 1024;  // HW adds lane*16
    char* const ldsB = (char*)&sB[0][0] + wv * 1024;

    f32x4 acc[8][4] = {};
    const int colX = (quad * 16) ^ ((c & 7) << 4);  // swizzled byte col, ksub0; ksub1 = ^64

    auto stageA = [&](int P, int chunk, int ktb) {
        const char* s0 = srcA + ktb + chunk * 131072;
        char* l0 = ldsA + P * 32768 + chunk * 16384;
        __builtin_amdgcn_global_load_lds((gptr_t)s0,            (lptr_t)l0,          16, 0, 0);
        __builtin_amdgcn_global_load_lds((gptr_t)(s0 + 262144), (lptr_t)(l0 + 8192), 16, 0, 0);
    };
    auto stageB = [&](int P, int chunk, int ktb) {
        const char* s0 = srcB + ktb + chunk * 131072;
        char* l0 = ldsB + P * 32768 + chunk * 16384;
        __builtin_amdgcn_global_load_lds((gptr_t)s0,            (lptr_t)l0,          16, 0, 0);
        __builtin_amdgcn_global_load_lds((gptr_t)(s0 + 524288), (lptr_t)(l0 + 8192), 16, 0, 0);
    };

    bf16x8 a[4][2], b0[2][2], b1[2][2];

    auto ldA = [&](int P, int ms) {
        const char* base = (const char*)&sA[0][0] + P * 32768 +
                           (size_t)(ms * 128 + wi * 64 + c) * 128;
        #pragma unroll
        for (int t = 0; t < 4; ++t) {
            a[t][0] = *(const bf16x8*)(base + t * 2048 + colX);
            a[t][1] = *(const bf16x8*)(base + t * 2048 + (colX ^ 64));
        }
    };
    auto ldB0 = [&](int P) {
        const char* base = (const char*)&sB[0][0] + P * 32768 +
                           (size_t)(wj * 32 + c) * 128;
        #pragma unroll
        for (int u = 0; u < 2; ++u) {
            b0[u][0] = *(const bf16x8*)(base + u * 2048 + colX);
            b0[u][1] = *(const bf16x8*)(base + u * 2048 + (colX ^ 64));
        }
    };
    auto ldB1 = [&](int P) {
        const char* base = (const char*)&sB[0][0] + P * 32768 + 16384 +
                           (size_t)(wj * 32 + c) * 128;
        #pragma unroll
        for (int u = 0; u < 2; ++u) {
            b1[u][0] = *(const bf16x8*)(base + u * 2048 + colX);
            b1[u][1] = *(const bf16x8*)(base + u * 2048 + (colX ^ 64));
        }
    };

    // ---- prologue: stage tile 0 into buf 0; queue = [Ac0 Bc0 Ac1 Bc1] ----
    stageA(0, 0, 0); stageB(0, 0, 0);
    stageA(0, 1, 0); stageB(0, 1, 0);
    ENDBAR(4);   // Ac0,Bc0 done; Ac1,Bc1 in flight (matches steady-state invariant)

    int kA = 64, kB = 128;  // src offsets for tile t+1
    for (int t = 0; t < 31; ++t) {
        const int P = t & 1, Q = P ^ 1;
        // PH1 (m0,n0)
        ldA(P, 0); ldB0(P);
        stageA(Q, 0, kA);
        MIDBAR();
        QUAD_MFMA(0, 0, b0);
        ENDBAR(2);           // forces Ac1(t),Bc1(t) complete
        // PH2 (m0,n1)
        ldB1(P);
        stageB(Q, 0, kB);
        MIDBAR();
        QUAD_MFMA(0, 1, b1);
        MIDBAR();
        // PH3 (m1,n1)
        ldA(P, 1);
        stageA(Q, 1, kA);
        MIDBAR();
        QUAD_MFMA(1, 1, b1);
        MIDBAR();
        // PH4 (m1,n0)
        stageB(Q, 1, kB);
        MIDBAR();
        QUAD_MFMA(1, 0, b0);
        ENDBAR(4);           // forces Ac0(t+1),Bc0(t+1) complete
        kA += 64; kB += 128;
    }
    // ---- epilogue tile 31 (buf 1): no staging; drain once ----
    ENDBAR(0);
    ldA(1, 0); ldB0(1); ldB1(1);
    QUAD_MFMA(0, 0, b0);
    QUAD_MFMA(0, 1, b1);
    ldA(1, 1);
    QUAD_MFMA(1, 1, b1);
    QUAD_MFMA(1, 0, b0);

    // ---- C write: col = lane&15, row = quad*4+r (verified layout) + bias ----
    #pragma unroll
    for (int n = 0; n < 4; ++n) {
        const int col = nbase + wj * 64 + (n >> 1) * 32 + (n & 1) * 16 + c;
        const float bv = bias[col];
        #pragma unroll
        for (int m = 0; m < 8; ++m) {
            const int row = mbase + wi * 128 + (m >> 2) * 64 + (m & 3) * 16 + quad * 4;
            #pragma unroll
            for (int r = 0; r < 4; ++r)
                Y[(size_t)(row + r) * DD + col] = (bf16_t)(acc[m][n][r] + bv);
        }
    }
}

// ---------------- local windowed attention (unchanged, verified) ----------------
__global__ __launch_bounds__(256) void attn_local(const bf16_t* __restrict__ Q,
                                                  const bf16_t* __restrict__ K,
                                                  const bf16_t* __restrict__ V,
                                                  bf16_t* __restrict__ ctx) {
    const int wx = blockIdx.x, h = blockIdx.y, b = blockIdx.z;
    const int tid  = threadIdx.x;
    const int lane = tid & 63;
    const int wv   = tid >> 6;
    const int c    = lane & 15;
    const int quad = lane >> 4;

    __shared__ alignas(16) bf16_t pbuf[128][136];
    __shared__ alignas(16) bf16_t vtb[64][136];

    const size_t base = ((size_t)b * SS + (size_t)wx * WW) * DD + (size_t)h * HD;

    for (int e = tid; e < WW * HD; e += 256) {
        int j = e >> 6, d = e & 63;
        vtb[d][j] = V[base + (size_t)j * DD + d];
    }

    const float scale = 0.125f;

    #pragma unroll
    for (int ii = 0; ii < 2; ++ii) {
        const int it = wv * 2 + ii;
        f32x4 s[8] = {};
        #pragma unroll
        for (int kt = 0; kt < 2; ++kt) {
            bf16x8 a = *(const bf16x8*)(Q + base + (size_t)(it * 16 + c) * DD + kt * 32 + quad * 8);
            #pragma unroll
            for (int jt = 0; jt < 8; ++jt) {
                bf16x8 bb = *(const bf16x8*)(K + base + (size_t)(jt * 16 + c) * DD + kt * 32 + quad * 8);
                s[jt] = mfma16(a, bb, s[jt]);
            }
        }
        #pragma unroll
        for (int jt = 0; jt < 8; ++jt) s[jt] *= scale;

        #pragma unroll
        for (int r = 0; r < 4; ++r) {
            float m = -1e30f;
            #pragma unroll
            for (int jt = 0; jt < 8; ++jt) m = fmaxf(m, s[jt][r]);
            #pragma unroll
            for (int off = 1; off < 16; off <<= 1) m = fmaxf(m, __shfl_xor(m, off));
            float p[8], sum = 0.f;
            #pragma unroll
            for (int jt = 0; jt < 8; ++jt) { p[jt] = __expf(s[jt][r] - m); sum += p[jt]; }
            #pragma unroll
            for (int off = 1; off < 16; off <<= 1) sum += __shfl_xor(sum, off);
            float inv = 1.0f / sum;
            int row = it * 16 + quad * 4 + r;
            #pragma unroll
            for (int jt = 0; jt < 8; ++jt) pbuf[row][jt * 16 + c] = (bf16_t)(p[jt] * inv);
        }
    }

    __syncthreads();

    #pragma unroll
    for (int ii = 0; ii < 2; ++ii) {
        const int it = wv * 2 + ii;
        f32x4 o[4] = {};
        #pragma unroll
        for (int kt = 0; kt < 4; ++kt) {
            bf16x8 a = *(const bf16x8*)&pbuf[it * 16 + c][kt * 32 + quad * 8];
            #pragma unroll
            for (int dt = 0; dt < 4; ++dt) {
                bf16x8 bb = *(const bf16x8*)&vtb[dt * 16 + c][kt * 32 + quad * 8];
                o[dt] = mfma16(a, bb, o[dt]);
            }
        }
        #pragma unroll
        for (int dt = 0; dt < 4; ++dt)
            #pragma unroll
            for (int r = 0; r < 4; ++r)
                ctx[base + (size_t)(it * 16 + quad * 4 + r) * DD + dt * 16 + c] = (bf16_t)(o[dt][r]);
    }
}

// ---------------- global-token attention (unchanged, verified) ----------------
__global__ __launch_bounds__(256) void attn_global(const bf16_t* __restrict__ Q,
                                                   const bf16_t* __restrict__ K,
                                                   const bf16_t* __restrict__ V,
                                                   const int* __restrict__ gidx,
                                                   bf16_t* __restrict__ ctx) {
    const int h = blockIdx.x, b = blockIdx.y;
    const int tid = threadIdx.x;

    __shared__ float qs[NG][HD], ks[NG][HD], vs[NG][HD];
    __shared__ float sc[NG][NG + 1];
    __shared__ int gi[NG];

    if (tid < NG) gi[tid] = gidx[tid];
    __syncthreads();

    for (int e = tid; e < NG * HD; e += 256) {
        int i = e >> 6, d = e & 63;
        size_t off = ((size_t)b * SS + gi[i]) * DD + (size_t)h * HD + d;
        qs[i][d] = (float)Q[off];
        ks[i][d] = (float)K[off];
        vs[i][d] = (float)V[off];
    }
    __syncthreads();

    for (int e = tid; e < NG * NG; e += 256) {
        int i = e >> 5, j = e & 31;
        float s = 0.f;
        #pragma unroll 8
        for (int d = 0; d < HD; ++d) s += qs[i][d] * ks[j][d];
        sc[i][j] = s * 0.125f;
    }
    __syncthreads();

    if (tid < NG) {
        float m = -1e30f;
        for (int j = 0; j < NG; ++j) m = fmaxf(m, sc[tid][j]);
        float sum = 0.f;
        for (int j = 0; j < NG; ++j) { float p = __expf(sc[tid][j] - m); sc[tid][j] = p; sum += p; }
        float inv = 1.f / sum;
        for (int j = 0; j < NG; ++j) sc[tid][j] *= inv;
    }
    __syncthreads();

    for (int e = tid; e < NG * HD; e += 256) {
        int i = e >> 6, d = e & 63;
        float o = 0.f;
        #pragma unroll 8
        for (int j = 0; j < NG; ++j) o += sc[i][j] * vs[j][d];
        ctx[((size_t)b * SS + gi[i]) * DD + (size_t)h * HD + d] = (bf16_t)o;
    }
}

extern "C" void kernel_launch(void* const* d_in, const int* in_sizes, int n_in,
                              void* d_out, int out_size, void* d_ws, size_t ws_size,
                              hipStream_t stream) {
    const void* query = d_in[0];
    const void* key_  = d_in[1];
    const void* value = d_in[2];
    const void* Wq = d_in[3];  const void* bq = d_in[4];
    const void* Wk = d_in[5];  const void* bk = d_in[6];
    const void* Wv = d_in[7];  const void* bv = d_in[8];
    const void* Wo = d_in[9];  const void* bo = d_in[10];
    const int* gidx = (const int*)d_in[11];

    const size_t nTok = (size_t)DB * SS * DD;   // 16,777,216 elems
    const size_t nW   = (size_t)DD * DD;        // 1,048,576 elems

    // ws layout:
    //   [0,4)        flag
    //   [256,16640)  bias f32[4096]
    //   [32768, +32MB)   Xh (reused per projection; later Y bf16)
    //   [+32MB, +64MB)   Qp
    //   [+64MB, +96MB)   Kp
    int*    flag    = (int*)d_ws;
    float*  biasbuf = (float*)((char*)d_ws + 256);
    bf16_t* Xh      = (bf16_t*)((char*)d_ws + 32768);
    bf16_t* Qp      = Xh + nTok;
    bf16_t* Kp      = Qp + nTok;
    bf16_t* Ybf     = Xh;  // final GEMM output (Xh dead by then)

    // d_out (64 MB) doubles as scratch:
    //   lo 32MB: W' slot for projections (4MB), then ctx
    //   hi 32MB: Vp, then W' slot for the output projection
    bf16_t* Wlo  = (bf16_t*)d_out;          // interleaved W' [1024][2048] = 4MB
    bf16_t* ctx  = (bf16_t*)d_out;
    bf16_t* Vp   = (bf16_t*)d_out + nTok;
    bf16_t* Whi  = Vp;                      // reused after attn

    detect_dtype<<<1, 64, 0, stream>>>((const unsigned short*)query, flag);
    cvt_bias<<<16, 256, 0, stream>>>(bq, bk, bv, bo, biasbuf, flag);

    cvt_w<<<1024, 256, 0, stream>>>(Wq, Wlo, flag);
    cvt_x<<<16384, 256, 0, stream>>>(query, Xh, flag);
    gemm8<<<256, 512, 0, stream>>>(Xh, Wlo, biasbuf + 0, Qp);

    cvt_w<<<1024, 256, 0, stream>>>(Wk, Wlo, flag);
    cvt_x<<<16384, 256, 0, stream>>>(key_, Xh, flag);
    gemm8<<<256, 512, 0, stream>>>(Xh, Wlo, biasbuf + 1024, Kp);

    cvt_w<<<1024, 256, 0, stream>>>(Wv, Wlo, flag);
    cvt_x<<<16384, 256, 0, stream>>>(value, Xh, flag);
    gemm8<<<256, 512, 0, stream>>>(Xh, Wlo, biasbuf + 2048, Vp);

    attn_local<<<dim3(NW, HH, DB), 256, 0, stream>>>(Qp, Kp, Vp, ctx);
    attn_global<<<dim3(HH, DB), 256, 0, stream>>>(Qp, Kp, Vp, gidx, ctx);

    cvt_w<<<1024, 256, 0, stream>>>(Wo, Whi, flag);
    gemm8<<<256, 512, 0, stream>>>(ctx, Whi, biasbuf + 3072, Ybf);
    expand_out<<<16384, 256, 0, stream>>>(Ybf, d_out, flag);
}

// Round 2
// 505.177 us; speedup vs baseline: 1.1671x; 1.1671x over previous
//
#include <hip/hip_runtime.h>

#define DB 4
#define SS 4096
#define DD 1024
#define HH 16
#define HD 64
#define WW 128
#define NW 32
#define NG 32

typedef __bf16 bf16_t;
typedef bf16_t bf16x4 __attribute__((ext_vector_type(4)));
typedef bf16_t bf16x8 __attribute__((ext_vector_type(8)));
typedef float f32x4 __attribute__((ext_vector_type(4)));

typedef const __attribute__((address_space(1))) void* gptr_t;
typedef __attribute__((address_space(3))) void* lptr_t;

static __device__ __forceinline__ f32x4 mfma16(bf16x8 a, bf16x8 b, f32x4 c) {
    return __builtin_amdgcn_mfma_f32_16x16x32_bf16(a, b, c, 0, 0, 0);
}

// ---------------- dtype probe (1 = buffers are bf16, 0 = f32) ----------------
__global__ void detect_dtype(const unsigned short* __restrict__ q, int* __restrict__ flag) {
    int lane = threadIdx.x;  // 64 threads
    unsigned short u = q[2 * lane];
    bf16_t b;
    __builtin_memcpy(&b, &u, 2);
    float v = fabsf((float)b);
    bool ok = (v > 1e-5f) && (v < 1e5f);
    unsigned long long m = __ballot(ok);
    if (lane == 0) *flag = (__popcll(m) >= 32) ? 1 : 0;
}

// ---------------- conversions ----------------
__global__ void cvt_x(const void* __restrict__ src, bf16_t* __restrict__ dst,
                      const int* __restrict__ flag) {
    int i = blockIdx.x * blockDim.x + threadIdx.x;  // one per 4 elems, 4M threads
    int e = i * 4;
    if (*flag) {
        *(ushort4*)(dst + e) = ((const ushort4*)src)[i];
    } else {
        float4 f = ((const float4*)src)[i];
        bf16x4 o = { (bf16_t)f.x, (bf16_t)f.y, (bf16_t)f.z, (bf16_t)f.w };
        *(bf16x4*)(dst + e) = o;
    }
}

// Plain bf16 weight conversion: W [1024][1024], same linear layout as src.
__global__ void cvt_w(const void* __restrict__ src, bf16_t* __restrict__ wp,
                      const int* __restrict__ flag) {
    int i = blockIdx.x * blockDim.x + threadIdx.x;  // one per 4 elems, 256K threads
    int e = i * 4;
    if (*flag) {
        *(ushort4*)(wp + e) = ((const ushort4*)src)[i];
    } else {
        float4 f = ((const float4*)src)[i];
        bf16x4 h = { (bf16_t)f.x, (bf16_t)f.y, (bf16_t)f.z, (bf16_t)f.w };
        *(bf16x4*)(wp + e) = h;
    }
}

__global__ void cvt_bias(const void* b0, const void* b1, const void* b2, const void* b3,
                         float* __restrict__ dst, const int* __restrict__ flag) {
    int i = blockIdx.x * blockDim.x + threadIdx.x;  // 4096
    const void* s = (i >> 10) == 0 ? b0 : (i >> 10) == 1 ? b1 : (i >> 10) == 2 ? b2 : b3;
    int j = i & 1023;
    dst[i] = (*flag) ? (float)((const bf16_t*)s)[j] : ((const float*)s)[j];
}

// ---------------- 8-phase 256x256 GEMM, K=1024, direct-dtype final write ----------------
// Y[m][n] = sum_k X[m][k]*W[n][k] + bias[n].
// 512 thr = 8 waves (2Mx4N), tile 256x256, BK=64, LDS 128KB (2 dbuf x (A 32K + B 32K)).
// LDS row = 64 elems = 128B, XOR-swizzle byte ^= ((ldsrow&7)<<4), both-sides (inverse on
// global source, forward on ds_read). Deltas preserve mod-8 row class, so srow&7 is valid.
// LDS row permutations (encoded in staging source deltas; readers depend on them):
//   A: lds rows {0-63,64-127,128-191,192-255} <- tile rows {0-63,128-191,64-127,192-255}
//      (e-delta = +128 rows = +262144B, chunk-delta = +64 rows = +131072B)
//   B: per-64 block n = ((srow>>5)<<6)+(srow&31); e-delta = +128 rows, chunk = +32 rows
//      -> lds rows map to n {0-31,64-95,128-159,192-223 | 32-63,96-127,160-191,224-255}
// Wait ledger (steady state, never drains):
//   end-ph1 vmcnt(2): Ac1(t),Bc1(t) complete; Ac0(t+1) stays in flight
//   end-ph4 vmcnt(4): Ac0(t+1),Bc0(t+1) complete; Ac1,Bc1(t+1) stay in flight
#define GFENCE() asm volatile("" ::: "memory")
#define MIDBAR() do { GFENCE(); __builtin_amdgcn_s_barrier(); GFENCE(); } while (0)
#define ENDBAR(N) do { asm volatile("s_waitcnt vmcnt(" #N ")" ::: "memory"); \
                       __builtin_amdgcn_s_barrier(); GFENCE(); } while (0)

#define QUAD_MFMA(MS, NS, BB)                                                          \
    do {                                                                               \
        __builtin_amdgcn_s_setprio(1);                                                 \
        _Pragma("unroll")                                                              \
        for (int t_ = 0; t_ < 4; ++t_) {                                               \
            _Pragma("unroll")                                                          \
            for (int u_ = 0; u_ < 2; ++u_) {                                           \
                acc[(MS)*4 + t_][(NS)*2 + u_] =                                        \
                    mfma16(a[t_][0], BB[u_][0], acc[(MS)*4 + t_][(NS)*2 + u_]);        \
                acc[(MS)*4 + t_][(NS)*2 + u_] =                                        \
                    mfma16(a[t_][1], BB[u_][1], acc[(MS)*4 + t_][(NS)*2 + u_]);        \
            }                                                                          \
        }                                                                              \
        __builtin_amdgcn_s_setprio(0);                                                 \
    } while (0)

__global__ __launch_bounds__(512, 2) void gemm8(const bf16_t* __restrict__ X,
                                                const bf16_t* __restrict__ Wp,
                                                const float* __restrict__ bias,
                                                void* __restrict__ Yout,
                                                const int* __restrict__ flag,
                                                int final_out) {
    __shared__ alignas(16) bf16_t sA[2][16384];   // 2 x 32KB
    __shared__ alignas(16) bf16_t sB[2][16384];   // 2 x 32KB

    const int tid  = threadIdx.x;
    const int lane = tid & 63;
    const int wv   = tid >> 6;
    const int c    = lane & 15;
    const int quad = lane >> 4;
    const int wi   = wv >> 2;   // 0..1 (M)
    const int wj   = wv & 3;    // 0..3 (N)

    const int f32out = final_out ? (*flag == 0) : 0;

    // XCD-aware bijective swizzle (nwg=256, 8 XCDs)
    int wg = blockIdx.x;
    wg = (wg & 7) * 32 + (wg >> 3);
    const int mbase = (wg >> 2) * 256;
    const int nbase = (wg & 3) * 256;

    // per-thread staging source base (chunk 0, e 0, ktile 0); inverse-swizzled source.
    const int d0   = tid * 16;
    const int srow = d0 >> 7;                       // 0..63
    const int scol = (d0 & 127) ^ ((srow & 7) << 4);
    const char* srcA = (const char*)X + (size_t)(mbase + srow) * 2048 + scol;
    const char* srcB = (const char*)Wp +
        (size_t)(nbase + ((srow >> 5) << 6) + (srow & 31)) * 2048 + scol;
    char* const ldsA = (char*)&sA[0][0] + wv * 1024;  // HW adds lane*16
    char* const ldsB = (char*)&sB[0][0] + wv * 1024;

    f32x4 acc[8][4] = {};
    const int colX = (quad * 16) ^ ((c & 7) << 4);  // swizzled byte col, ksub0; ksub1 = ^64

    auto stageA = [&](int P, int chunk, int ktb) {
        const char* s0 = srcA + ktb + chunk * 131072;   // chunk: +64 tile rows
        char* l0 = ldsA + P * 32768 + chunk * 16384;
        __builtin_amdgcn_global_load_lds((gptr_t)s0,            (lptr_t)l0,          16, 0, 0);
        __builtin_amdgcn_global_load_lds((gptr_t)(s0 + 262144), (lptr_t)(l0 + 8192), 16, 0, 0);
    };
    auto stageB = [&](int P, int chunk, int ktb) {
        const char* s0 = srcB + ktb + chunk * 65536;    // chunk: +32 n rows
        char* l0 = ldsB + P * 32768 + chunk * 16384;
        __builtin_amdgcn_global_load_lds((gptr_t)s0,            (lptr_t)l0,          16, 0, 0);
        __builtin_amdgcn_global_load_lds((gptr_t)(s0 + 262144), (lptr_t)(l0 + 8192), 16, 0, 0);
    };

    bf16x8 a[4][2], b0[2][2], b1[2][2];

    auto ldA = [&](int P, int ms) {
        const char* base = (const char*)&sA[0][0] + P * 32768 +
                           (size_t)(ms * 128 + wi * 64 + c) * 128;
        #pragma unroll
        for (int t = 0; t < 4; ++t) {
            a[t][0] = *(const bf16x8*)(base + t * 2048 + colX);
            a[t][1] = *(const bf16x8*)(base + t * 2048 + (colX ^ 64));
        }
    };
    auto ldB0 = [&](int P) {
        const char* base = (const char*)&sB[0][0] + P * 32768 +
                           (size_t)(wj * 32 + c) * 128;
        #pragma unroll
        for (int u = 0; u < 2; ++u) {
            b0[u][0] = *(const bf16x8*)(base + u * 2048 + colX);
            b0[u][1] = *(const bf16x8*)(base + u * 2048 + (colX ^ 64));
        }
    };
    auto ldB1 = [&](int P) {
        const char* base = (const char*)&sB[0][0] + P * 32768 + 16384 +
                           (size_t)(wj * 32 + c) * 128;
        #pragma unroll
        for (int u = 0; u < 2; ++u) {
            b1[u][0] = *(const bf16x8*)(base + u * 2048 + colX);
            b1[u][1] = *(const bf16x8*)(base + u * 2048 + (colX ^ 64));
        }
    };

    // ---- prologue: stage tile 0 into buf 0; queue = [Ac0 Bc0 Ac1 Bc1] ----
    stageA(0, 0, 0); stageB(0, 0, 0);
    stageA(0, 1, 0); stageB(0, 1, 0);
    ENDBAR(4);   // Ac0,Bc0 done; Ac1,Bc1 in flight (steady-state invariant)

    int kk = 128;  // src k-byte offset for tile t+1 (64 k-elems * 2B per tile)
    for (int t = 0; t < 15; ++t) {
        const int P = t & 1, Q = P ^ 1;
        // PH1 (m0,n0)
        ldA(P, 0); ldB0(P);
        stageA(Q, 0, kk);
        MIDBAR();
        QUAD_MFMA(0, 0, b0);
        ENDBAR(2);           // forces Ac1(t),Bc1(t) complete
        // PH2 (m0,n1)
        ldB1(P);
        stageB(Q, 0, kk);
        MIDBAR();
        QUAD_MFMA(0, 1, b1);
        MIDBAR();
        // PH3 (m1,n1)
        ldA(P, 1);
        stageA(Q, 1, kk);
        MIDBAR();
        QUAD_MFMA(1, 1, b1);
        MIDBAR();
        // PH4 (m1,n0)
        stageB(Q, 1, kk);
        MIDBAR();
        QUAD_MFMA(1, 0, b0);
        ENDBAR(4);           // forces Ac0(t+1),Bc0(t+1) complete
        kk += 128;
    }
    // ---- epilogue tile 15 (buf 1): no staging; drain once ----
    ENDBAR(0);
    ldA(1, 0); ldB0(1); ldB1(1);
    QUAD_MFMA(0, 0, b0);
    QUAD_MFMA(0, 1, b1);
    ldA(1, 1);
    QUAD_MFMA(1, 1, b1);
    QUAD_MFMA(1, 0, b0);

    // ---- C write: col = lane&15, row = quad*4+r + bias; final writes harness dtype ----
    #pragma unroll
    for (int n = 0; n < 4; ++n) {
        const int col = nbase + wj * 64 + (n >> 1) * 32 + (n & 1) * 16 + c;
        const float bv = bias[col];
        #pragma unroll
        for (int m = 0; m < 8; ++m) {
            const int row = mbase + wi * 128 + (m >> 2) * 64 + (m & 3) * 16 + quad * 4;
            #pragma unroll
            for (int r = 0; r < 4; ++r) {
                const float yv = acc[m][n][r] + bv;
                const size_t idx = (size_t)(row + r) * DD + col;
                if (f32out) ((float*)Yout)[idx] = yv;
                else        ((bf16_t*)Yout)[idx] = (bf16_t)yv;
            }
        }
    }
}

// ---------------- local windowed attention (unchanged, verified) ----------------
__global__ __launch_bounds__(256) void attn_local(const bf16_t* __restrict__ Q,
                                                  const bf16_t* __restrict__ K,
                                                  const bf16_t* __restrict__ V,
                                                  bf16_t* __restrict__ ctx) {
    const int wx = blockIdx.x, h = blockIdx.y, b = blockIdx.z;
    const int tid  = threadIdx.x;
    const int lane = tid & 63;
    const int wv   = tid >> 6;
    const int c    = lane & 15;
    const int quad = lane >> 4;

    __shared__ alignas(16) bf16_t pbuf[128][136];
    __shared__ alignas(16) bf16_t vtb[64][136];

    const size_t base = ((size_t)b * SS + (size_t)wx * WW) * DD + (size_t)h * HD;

    for (int e = tid; e < WW * HD; e += 256) {
        int j = e >> 6, d = e & 63;
        vtb[d][j] = V[base + (size_t)j * DD + d];
    }

    const float scale = 0.125f;

    #pragma unroll
    for (int ii = 0; ii < 2; ++ii) {
        const int it = wv * 2 + ii;
        f32x4 s[8] = {};
        #pragma unroll
        for (int kt = 0; kt < 2; ++kt) {
            bf16x8 a = *(const bf16x8*)(Q + base + (size_t)(it * 16 + c) * DD + kt * 32 + quad * 8);
            #pragma unroll
            for (int jt = 0; jt < 8; ++jt) {
                bf16x8 bb = *(const bf16x8*)(K + base + (size_t)(jt * 16 + c) * DD + kt * 32 + quad * 8);
                s[jt] = mfma16(a, bb, s[jt]);
            }
        }
        #pragma unroll
        for (int jt = 0; jt < 8; ++jt) s[jt] *= scale;

        #pragma unroll
        for (int r = 0; r < 4; ++r) {
            float m = -1e30f;
            #pragma unroll
            for (int jt = 0; jt < 8; ++jt) m = fmaxf(m, s[jt][r]);
            #pragma unroll
            for (int off = 1; off < 16; off <<= 1) m = fmaxf(m, __shfl_xor(m, off));
            float p[8], sum = 0.f;
            #pragma unroll
            for (int jt = 0; jt < 8; ++jt) { p[jt] = __expf(s[jt][r] - m); sum += p[jt]; }
            #pragma unroll
            for (int off = 1; off < 16; off <<= 1) sum += __shfl_xor(sum, off);
            float inv = 1.0f / sum;
            int row = it * 16 + quad * 4 + r;
            #pragma unroll
            for (int jt = 0; jt < 8; ++jt) pbuf[row][jt * 16 + c] = (bf16_t)(p[jt] * inv);
        }
    }

    __syncthreads();

    #pragma unroll
    for (int ii = 0; ii < 2; ++ii) {
        const int it = wv * 2 + ii;
        f32x4 o[4] = {};
        #pragma unroll
        for (int kt = 0; kt < 4; ++kt) {
            bf16x8 a = *(const bf16x8*)&pbuf[it * 16 + c][kt * 32 + quad * 8];
            #pragma unroll
            for (int dt = 0; dt < 4; ++dt) {
                bf16x8 bb = *(const bf16x8*)&vtb[dt * 16 + c][kt * 32 + quad * 8];
                o[dt] = mfma16(a, bb, o[dt]);
            }
        }
        #pragma unroll
        for (int dt = 0; dt < 4; ++dt)
            #pragma unroll
            for (int r = 0; r < 4; ++r)
                ctx[base + (size_t)(it * 16 + quad * 4 + r) * DD + dt * 16 + c] = (bf16_t)(o[dt][r]);
    }
}

// ---------------- global-token attention (unchanged, verified) ----------------
__global__ __launch_bounds__(256) void attn_global(const bf16_t* __restrict__ Q,
                                                   const bf16_t* __restrict__ K,
                                                   const bf16_t* __restrict__ V,
                                                   const int* __restrict__ gidx,
                                                   bf16_t* __restrict__ ctx) {
    const int h = blockIdx.x, b = blockIdx.y;
    const int tid = threadIdx.x;

    __shared__ float qs[NG][HD], ks[NG][HD], vs[NG][HD];
    __shared__ float sc[NG][NG + 1];
    __shared__ int gi[NG];

    if (tid < NG) gi[tid] = gidx[tid];
    __syncthreads();

    for (int e = tid; e < NG * HD; e += 256) {
        int i = e >> 6, d = e & 63;
        size_t off = ((size_t)b * SS + gi[i]) * DD + (size_t)h * HD + d;
        qs[i][d] = (float)Q[off];
        ks[i][d] = (float)K[off];
        vs[i][d] = (float)V[off];
    }
    __syncthreads();

    for (int e = tid; e < NG * NG; e += 256) {
        int i = e >> 5, j = e & 31;
        float s = 0.f;
        #pragma unroll 8
        for (int d = 0; d < HD; ++d) s += qs[i][d] * ks[j][d];
        sc[i][j] = s * 0.125f;
    }
    __syncthreads();

    if (tid < NG) {
        float m = -1e30f;
        for (int j = 0; j < NG; ++j) m = fmaxf(m, sc[tid][j]);
        float sum = 0.f;
        for (int j = 0; j < NG; ++j) { float p = __expf(sc[tid][j] - m); sc[tid][j] = p; sum += p; }
        float inv = 1.f / sum;
        for (int j = 0; j < NG; ++j) sc[tid][j] *= inv;
    }
    __syncthreads();

    for (int e = tid; e < NG * HD; e += 256) {
        int i = e >> 6, d = e & 63;
        float o = 0.f;
        #pragma unroll 8
        for (int j = 0; j < NG; ++j) o += sc[i][j] * vs[j][d];
        ctx[((size_t)b * SS + gi[i]) * DD + (size_t)h * HD + d] = (bf16_t)o;
    }
}

extern "C" void kernel_launch(void* const* d_in, const int* in_sizes, int n_in,
                              void* d_out, int out_size, void* d_ws, size_t ws_size,
                              hipStream_t stream) {
    const void* query = d_in[0];
    const void* key_  = d_in[1];
    const void* value = d_in[2];
    const void* Wq = d_in[3];  const void* bq = d_in[4];
    const void* Wk = d_in[5];  const void* bk = d_in[6];
    const void* Wv = d_in[7];  const void* bv = d_in[8];
    const void* Wo = d_in[9];  const void* bo = d_in[10];
    const int* gidx = (const int*)d_in[11];

    const size_t nTok = (size_t)DB * SS * DD;   // 16,777,216 elems

    // ws layout (~96 MB):
    //   [0,4)        flag
    //   [256,16640)  bias f32[4096]
    //   [32768, +32MB)   Xh (per-projection input; after attn: ctx)
    //   [+32MB, +64MB)   Qp
    //   [+64MB, +96MB)   Kp (after attn: Wo' slot)
    int*    flag    = (int*)d_ws;
    float*  biasbuf = (float*)((char*)d_ws + 256);
    bf16_t* Xh      = (bf16_t*)((char*)d_ws + 32768);
    bf16_t* Qp      = Xh + nTok;
    bf16_t* Kp      = Qp + nTok;
    bf16_t* ctx     = Xh;   // Xh dead after V projection
    bf16_t* Wop     = Kp;   // Kp dead after attention

    // d_out (64 MB) doubles as scratch until the final GEMM owns it:
    //   lo 2MB: W slot for the three projections ; hi 32MB: Vp
    bf16_t* Wlo = (bf16_t*)d_out;
    bf16_t* Vp  = (bf16_t*)d_out + nTok;

    detect_dtype<<<1, 64, 0, stream>>>((const unsigned short*)query, flag);
    cvt_bias<<<16, 256, 0, stream>>>(bq, bk, bv, bo, biasbuf, flag);

    cvt_w<<<1024, 256, 0, stream>>>(Wq, Wlo, flag);
    cvt_x<<<16384, 256, 0, stream>>>(query, Xh, flag);
    gemm8<<<256, 512, 0, stream>>>(Xh, Wlo, biasbuf + 0, Qp, flag, 0);

    cvt_w<<<1024, 256, 0, stream>>>(Wk, Wlo, flag);
    cvt_x<<<16384, 256, 0, stream>>>(key_, Xh, flag);
    gemm8<<<256, 512, 0, stream>>>(Xh, Wlo, biasbuf + 1024, Kp, flag, 0);

    cvt_w<<<1024, 256, 0, stream>>>(Wv, Wlo, flag);
    cvt_x<<<16384, 256, 0, stream>>>(value, Xh, flag);
    gemm8<<<256, 512, 0, stream>>>(Xh, Wlo, biasbuf + 2048, Vp, flag, 0);

    attn_local<<<dim3(NW, HH, DB), 256, 0, stream>>>(Qp, Kp, Vp, ctx);
    attn_global<<<dim3(HH, DB), 256, 0, stream>>>(Qp, Kp, Vp, gidx, ctx);

    cvt_w<<<1024, 256, 0, stream>>>(Wo, Wop, flag);
    gemm8<<<256, 512, 0, stream>>>(ctx, Wop, biasbuf + 3072, d_out, flag, 1);
}

// Round 3
// 494.596 us; speedup vs baseline: 1.1920x; 1.0214x over previous
//
#include <hip/hip_runtime.h>

#define DB 4
#define SS 4096
#define DD 1024
#define HH 16
#define HD 64
#define WW 128
#define NW 32
#define NG 32

typedef __bf16 bf16_t;
typedef bf16_t bf16x4 __attribute__((ext_vector_type(4)));
typedef bf16_t bf16x8 __attribute__((ext_vector_type(8)));
typedef float f32x4 __attribute__((ext_vector_type(4)));

typedef const __attribute__((address_space(1))) void* gptr_t;
typedef __attribute__((address_space(3))) void* lptr_t;

static __device__ __forceinline__ f32x4 mfma16(bf16x8 a, bf16x8 b, f32x4 c) {
    return __builtin_amdgcn_mfma_f32_16x16x32_bf16(a, b, c, 0, 0, 0);
}

// ---------------- dtype probe + bias conversion (merged, 1 block) ----------------
__global__ void detect_and_bias(const unsigned short* __restrict__ q, int* __restrict__ flag,
                                const void* b0, const void* b1, const void* b2, const void* b3,
                                float* __restrict__ dst) {
    __shared__ int sflag;
    int tid = threadIdx.x;  // 256
    if (tid < 64) {
        unsigned short u = q[2 * tid];
        bf16_t b;
        __builtin_memcpy(&b, &u, 2);
        float v = fabsf((float)b);
        bool ok = (v > 1e-5f) && (v < 1e5f);
        unsigned long long m = __ballot(ok);
        if (tid == 0) { int f = (__popcll(m) >= 32) ? 1 : 0; *flag = f; sflag = f; }
    }
    __syncthreads();
    const int f = sflag;
    for (int i = tid; i < 4096; i += 256) {
        const void* s = (i >> 10) == 0 ? b0 : (i >> 10) == 1 ? b1 : (i >> 10) == 2 ? b2 : b3;
        int j = i & 1023;
        dst[i] = f ? (float)((const bf16_t*)s)[j] : ((const float*)s)[j];
    }
}

// ---------------- conversions ----------------
__global__ void cvt_x(const void* __restrict__ src, bf16_t* __restrict__ dst,
                      const int* __restrict__ flag) {
    int i = blockIdx.x * blockDim.x + threadIdx.x;  // one per 4 elems, 4M threads
    int e = i * 4;
    if (*flag) {
        *(ushort4*)(dst + e) = ((const ushort4*)src)[i];
    } else {
        float4 f = ((const float4*)src)[i];
        bf16x4 o = { (bf16_t)f.x, (bf16_t)f.y, (bf16_t)f.z, (bf16_t)f.w };
        *(bf16x4*)(dst + e) = o;
    }
}

// Plain bf16 weight conversion: W [1024][1024], same linear layout as src.
__global__ void cvt_w(const void* __restrict__ src, bf16_t* __restrict__ wp,
                      const int* __restrict__ flag) {
    int i = blockIdx.x * blockDim.x + threadIdx.x;  // one per 4 elems, 256K threads
    int e = i * 4;
    if (*flag) {
        *(ushort4*)(wp + e) = ((const ushort4*)src)[i];
    } else {
        float4 f = ((const float4*)src)[i];
        bf16x4 h = { (bf16_t)f.x, (bf16_t)f.y, (bf16_t)f.z, (bf16_t)f.w };
        *(bf16x4*)(wp + e) = h;
    }
}

// ---------------- 8-phase 256x256 GEMM, K=1024, direct-dtype final write ----------------
// (unchanged from round 2 — verified)
#define GFENCE() asm volatile("" ::: "memory")
#define MIDBAR() do { GFENCE(); __builtin_amdgcn_s_barrier(); GFENCE(); } while (0)
#define ENDBAR(N) do { asm volatile("s_waitcnt vmcnt(" #N ")" ::: "memory"); \
                       __builtin_amdgcn_s_barrier(); GFENCE(); } while (0)

#define QUAD_MFMA(MS, NS, BB)                                                          \
    do {                                                                               \
        __builtin_amdgcn_s_setprio(1);                                                 \
        _Pragma("unroll")                                                              \
        for (int t_ = 0; t_ < 4; ++t_) {                                               \
            _Pragma("unroll")                                                          \
            for (int u_ = 0; u_ < 2; ++u_) {                                           \
                acc[(MS)*4 + t_][(NS)*2 + u_] =                                        \
                    mfma16(a[t_][0], BB[u_][0], acc[(MS)*4 + t_][(NS)*2 + u_]);        \
                acc[(MS)*4 + t_][(NS)*2 + u_] =                                        \
                    mfma16(a[t_][1], BB[u_][1], acc[(MS)*4 + t_][(NS)*2 + u_]);        \
            }                                                                          \
        }                                                                              \
        __builtin_amdgcn_s_setprio(0);                                                 \
    } while (0)

__global__ __launch_bounds__(512, 2) void gemm8(const bf16_t* __restrict__ X,
                                                const bf16_t* __restrict__ Wp,
                                                const float* __restrict__ bias,
                                                void* __restrict__ Yout,
                                                const int* __restrict__ flag,
                                                int final_out) {
    __shared__ alignas(16) bf16_t sA[2][16384];   // 2 x 32KB
    __shared__ alignas(16) bf16_t sB[2][16384];   // 2 x 32KB

    const int tid  = threadIdx.x;
    const int lane = tid & 63;
    const int wv   = tid >> 6;
    const int c    = lane & 15;
    const int quad = lane >> 4;
    const int wi   = wv >> 2;   // 0..1 (M)
    const int wj   = wv & 3;    // 0..3 (N)

    const int f32out = final_out ? (*flag == 0) : 0;

    // XCD-aware bijective swizzle (nwg=256, 8 XCDs)
    int wg = blockIdx.x;
    wg = (wg & 7) * 32 + (wg >> 3);
    const int mbase = (wg >> 2) * 256;
    const int nbase = (wg & 3) * 256;

    // per-thread staging source base (chunk 0, e 0, ktile 0); inverse-swizzled source.
    const int d0   = tid * 16;
    const int srow = d0 >> 7;                       // 0..63
    const int scol = (d0 & 127) ^ ((srow & 7) << 4);
    const char* srcA = (const char*)X + (size_t)(mbase + srow) * 2048 + scol;
    const char* srcB = (const char*)Wp +
        (size_t)(nbase + ((srow >> 5) << 6) + (srow & 31)) * 2048 + scol;
    char* const ldsA = (char*)&sA[0][0] + wv * 1024;  // HW adds lane*16
    char* const ldsB = (char*)&sB[0][0] + wv * 1024;

    f32x4 acc[8][4] = {};
    const int colX = (quad * 16) ^ ((c & 7) << 4);  // swizzled byte col, ksub0; ksub1 = ^64

    auto stageA = [&](int P, int chunk, int ktb) {
        const char* s0 = srcA + ktb + chunk * 131072;   // chunk: +64 tile rows
        char* l0 = ldsA + P * 32768 + chunk * 16384;
        __builtin_amdgcn_global_load_lds((gptr_t)s0,            (lptr_t)l0,          16, 0, 0);
        __builtin_amdgcn_global_load_lds((gptr_t)(s0 + 262144), (lptr_t)(l0 + 8192), 16, 0, 0);
    };
    auto stageB = [&](int P, int chunk, int ktb) {
        const char* s0 = srcB + ktb + chunk * 65536;    // chunk: +32 n rows
        char* l0 = ldsB + P * 32768 + chunk * 16384;
        __builtin_amdgcn_global_load_lds((gptr_t)s0,            (lptr_t)l0,          16, 0, 0);
        __builtin_amdgcn_global_load_lds((gptr_t)(s0 + 262144), (lptr_t)(l0 + 8192), 16, 0, 0);
    };

    bf16x8 a[4][2], b0[2][2], b1[2][2];

    auto ldA = [&](int P, int ms) {
        const char* base = (const char*)&sA[0][0] + P * 32768 +
                           (size_t)(ms * 128 + wi * 64 + c) * 128;
        #pragma unroll
        for (int t = 0; t < 4; ++t) {
            a[t][0] = *(const bf16x8*)(base + t * 2048 + colX);
            a[t][1] = *(const bf16x8*)(base + t * 2048 + (colX ^ 64));
        }
    };
    auto ldB0 = [&](int P) {
        const char* base = (const char*)&sB[0][0] + P * 32768 +
                           (size_t)(wj * 32 + c) * 128;
        #pragma unroll
        for (int u = 0; u < 2; ++u) {
            b0[u][0] = *(const bf16x8*)(base + u * 2048 + colX);
            b0[u][1] = *(const bf16x8*)(base + u * 2048 + (colX ^ 64));
        }
    };
    auto ldB1 = [&](int P) {
        const char* base = (const char*)&sB[0][0] + P * 32768 + 16384 +
                           (size_t)(wj * 32 + c) * 128;
        #pragma unroll
        for (int u = 0; u < 2; ++u) {
            b1[u][0] = *(const bf16x8*)(base + u * 2048 + colX);
            b1[u][1] = *(const bf16x8*)(base + u * 2048 + (colX ^ 64));
        }
    };

    // ---- prologue: stage tile 0 into buf 0; queue = [Ac0 Bc0 Ac1 Bc1] ----
    stageA(0, 0, 0); stageB(0, 0, 0);
    stageA(0, 1, 0); stageB(0, 1, 0);
    ENDBAR(4);   // Ac0,Bc0 done; Ac1,Bc1 in flight (steady-state invariant)

    int kk = 128;  // src k-byte offset for tile t+1 (64 k-elems * 2B per tile)
    for (int t = 0; t < 15; ++t) {
        const int P = t & 1, Q = P ^ 1;
        // PH1 (m0,n0)
        ldA(P, 0); ldB0(P);
        stageA(Q, 0, kk);
        MIDBAR();
        QUAD_MFMA(0, 0, b0);
        ENDBAR(2);           // forces Ac1(t),Bc1(t) complete
        // PH2 (m0,n1)
        ldB1(P);
        stageB(Q, 0, kk);
        MIDBAR();
        QUAD_MFMA(0, 1, b1);
        MIDBAR();
        // PH3 (m1,n1)
        ldA(P, 1);
        stageA(Q, 1, kk);
        MIDBAR();
        QUAD_MFMA(1, 1, b1);
        MIDBAR();
        // PH4 (m1,n0)
        stageB(Q, 1, kk);
        MIDBAR();
        QUAD_MFMA(1, 0, b0);
        ENDBAR(4);           // forces Ac0(t+1),Bc0(t+1) complete
        kk += 128;
    }
    // ---- epilogue tile 15 (buf 1): no staging; drain once ----
    ENDBAR(0);
    ldA(1, 0); ldB0(1); ldB1(1);
    QUAD_MFMA(0, 0, b0);
    QUAD_MFMA(0, 1, b1);
    ldA(1, 1);
    QUAD_MFMA(1, 1, b1);
    QUAD_MFMA(1, 0, b0);

    // ---- C write: col = lane&15, row = quad*4+r + bias; final writes harness dtype ----
    #pragma unroll
    for (int n = 0; n < 4; ++n) {
        const int col = nbase + wj * 64 + (n >> 1) * 32 + (n & 1) * 16 + c;
        const float bv = bias[col];
        #pragma unroll
        for (int m = 0; m < 8; ++m) {
            const int row = mbase + wi * 128 + (m >> 2) * 64 + (m & 3) * 16 + quad * 4;
            #pragma unroll
            for (int r = 0; r < 4; ++r) {
                const float yv = acc[m][n][r] + bv;
                const size_t idx = (size_t)(row + r) * DD + col;
                if (f32out) ((float*)Yout)[idx] = yv;
                else        ((bf16_t*)Yout)[idx] = (bf16_t)yv;
            }
        }
    }
}

// ---------------- local windowed attention (reg-hoisted K/Q, swizzled pbuf) ----------------
// Per block: one (window, head, batch). 4 waves x 32 Q rows. Changes vs verified r2:
//  - all K (16) and Q (4) fragments loaded to regs up-front (launch_bounds(256,3) for VGPR)
//  - pbuf [128][128] + XOR swizzle byte^=(row&7)<<4 on both scalar write and b128 read
//  - vtb staged per-(d, j-block): 8 coalesced row reads -> one ds_write_b128 (no 8-way
//    transpose-write conflicts)
__global__ __launch_bounds__(256, 3) void attn_local(const bf16_t* __restrict__ Q,
                                                     const bf16_t* __restrict__ K,
                                                     const bf16_t* __restrict__ V,
                                                     bf16_t* __restrict__ ctx) {
    const int wx = blockIdx.x, h = blockIdx.y, b = blockIdx.z;
    const int tid  = threadIdx.x;
    const int lane = tid & 63;
    const int wv   = tid >> 6;
    const int c    = lane & 15;
    const int quad = lane >> 4;

    __shared__ alignas(16) bf16_t pbuf[128][128];   // XOR-swizzled, 32KB
    __shared__ alignas(16) bf16_t vtb[64][136];     // V^T, 17.4KB

    const size_t base = ((size_t)b * SS + (size_t)wx * WW) * DD + (size_t)h * HD;

    // ---- hoisted K/Q fragment loads (issued before V staging; one latency exposure) ----
    bf16x8 kf[8][2], qf[2][2];
    #pragma unroll
    for (int jt = 0; jt < 8; ++jt)
        #pragma unroll
        for (int kt = 0; kt < 2; ++kt)
            kf[jt][kt] = *(const bf16x8*)(K + base + (size_t)(jt * 16 + c) * DD + kt * 32 + quad * 8);
    #pragma unroll
    for (int ii = 0; ii < 2; ++ii)
        #pragma unroll
        for (int kt = 0; kt < 2; ++kt)
            qf[ii][kt] = *(const bf16x8*)(Q + base + (size_t)((wv * 2 + ii) * 16 + c) * DD + kt * 32 + quad * 8);

    // ---- V^T staging: thread owns (d = tid&63, j-block = (tid>>6)*8 + pass*32) ----
    {
        const int vd  = tid & 63;
        const int vj0 = (tid >> 6) * 8;
        #pragma unroll
        for (int pass = 0; pass < 4; ++pass) {
            const int j0 = vj0 + pass * 32;
            bf16_t tmp[8];
            #pragma unroll
            for (int u = 0; u < 8; ++u)
                tmp[u] = V[base + (size_t)(j0 + u) * DD + vd];   // coalesced 128B rows
            *(bf16x8*)&vtb[vd][j0] = *(const bf16x8*)tmp;        // b128, baseline banks
        }
    }

    const float scale = 0.125f;

    #pragma unroll
    for (int ii = 0; ii < 2; ++ii) {
        const int it = wv * 2 + ii;
        f32x4 s[8] = {};
        #pragma unroll
        for (int kt = 0; kt < 2; ++kt)
            #pragma unroll
            for (int jt = 0; jt < 8; ++jt)
                s[jt] = mfma16(qf[ii][kt], kf[jt][kt], s[jt]);
        #pragma unroll
        for (int jt = 0; jt < 8; ++jt) s[jt] *= scale;

        #pragma unroll
        for (int r = 0; r < 4; ++r) {
            float m = -1e30f;
            #pragma unroll
            for (int jt = 0; jt < 8; ++jt) m = fmaxf(m, s[jt][r]);
            #pragma unroll
            for (int off = 1; off < 16; off <<= 1) m = fmaxf(m, __shfl_xor(m, off));
            float p[8], sum = 0.f;
            #pragma unroll
            for (int jt = 0; jt < 8; ++jt) { p[jt] = __expf(s[jt][r] - m); sum += p[jt]; }
            #pragma unroll
            for (int off = 1; off < 16; off <<= 1) sum += __shfl_xor(sum, off);
            float inv = 1.0f / sum;
            const int row = it * 16 + quad * 4 + r;
            char* pb = (char*)pbuf;
            #pragma unroll
            for (int jt = 0; jt < 8; ++jt)
                *(bf16_t*)(pb + ((row * 256 + (jt * 16 + c) * 2) ^ ((row & 7) << 4))) =
                    (bf16_t)(p[jt] * inv);
        }
    }

    __syncthreads();

    #pragma unroll
    for (int ii = 0; ii < 2; ++ii) {
        const int it = wv * 2 + ii;
        const int prow = it * 16 + c;
        const char* pb = (const char*)pbuf;
        f32x4 o[4] = {};
        #pragma unroll
        for (int kt = 0; kt < 4; ++kt) {
            bf16x8 a = *(const bf16x8*)(pb +
                ((prow * 256 + (kt * 32 + quad * 8) * 2) ^ ((prow & 7) << 4)));
            #pragma unroll
            for (int dt = 0; dt < 4; ++dt) {
                bf16x8 bb = *(const bf16x8*)&vtb[dt * 16 + c][kt * 32 + quad * 8];
                o[dt] = mfma16(a, bb, o[dt]);
            }
        }
        #pragma unroll
        for (int dt = 0; dt < 4; ++dt)
            #pragma unroll
            for (int r = 0; r < 4; ++r)
                ctx[base + (size_t)(it * 16 + quad * 4 + r) * DD + dt * 16 + c] = (bf16_t)(o[dt][r]);
    }
}

// ---------------- global-token attention (parallel softmax) ----------------
__global__ __launch_bounds__(256) void attn_global(const bf16_t* __restrict__ Q,
                                                   const bf16_t* __restrict__ K,
                                                   const bf16_t* __restrict__ V,
                                                   const int* __restrict__ gidx,
                                                   bf16_t* __restrict__ ctx) {
    const int h = blockIdx.x, b = blockIdx.y;
    const int tid = threadIdx.x;

    __shared__ float qs[NG][HD], ks[NG][HD], vs[NG][HD];
    __shared__ float sc[NG][NG + 1];
    __shared__ int gi[NG];

    if (tid < NG) gi[tid] = gidx[tid];
    __syncthreads();

    for (int e = tid; e < NG * HD; e += 256) {
        int i = e >> 6, d = e & 63;
        size_t off = ((size_t)b * SS + gi[i]) * DD + (size_t)h * HD + d;
        qs[i][d] = (float)Q[off];
        ks[i][d] = (float)K[off];
        vs[i][d] = (float)V[off];
    }
    __syncthreads();

    for (int e = tid; e < NG * NG; e += 256) {
        int i = e >> 5, j = e & 31;
        float s = 0.f;
        #pragma unroll 8
        for (int d = 0; d < HD; ++d) s += qs[i][d] * ks[j][d];
        sc[i][j] = s * 0.125f;
    }
    __syncthreads();

    // each 32-lane half-wave owns one row: shfl-parallel softmax
    for (int i = tid >> 5; i < NG; i += 8) {
        const int j = tid & 31;
        float v = sc[i][j];
        float m = v;
        #pragma unroll
        for (int off = 1; off < 32; off <<= 1) m = fmaxf(m, __shfl_xor(m, off));
        float p = __expf(v - m);
        float s = p;
        #pragma unroll
        for (int off = 1; off < 32; off <<= 1) s += __shfl_xor(s, off);
        sc[i][j] = p / s;
    }
    __syncthreads();

    for (int e = tid; e < NG * HD; e += 256) {
        int i = e >> 6, d = e & 63;
        float o = 0.f;
        #pragma unroll 8
        for (int j = 0; j < NG; ++j) o += sc[i][j] * vs[j][d];
        ctx[((size_t)b * SS + gi[i]) * DD + (size_t)h * HD + d] = (bf16_t)o;
    }
}

extern "C" void kernel_launch(void* const* d_in, const int* in_sizes, int n_in,
                              void* d_out, int out_size, void* d_ws, size_t ws_size,
                              hipStream_t stream) {
    const void* query = d_in[0];
    const void* key_  = d_in[1];
    const void* value = d_in[2];
    const void* Wq = d_in[3];  const void* bq = d_in[4];
    const void* Wk = d_in[5];  const void* bk = d_in[6];
    const void* Wv = d_in[7];  const void* bv = d_in[8];
    const void* Wo = d_in[9];  const void* bo = d_in[10];
    const int* gidx = (const int*)d_in[11];

    const size_t nTok = (size_t)DB * SS * DD;   // 16,777,216 elems

    // ws layout (~96 MB):
    //   [0,4)        flag
    //   [256,16640)  bias f32[4096]
    //   [32768, +32MB)   Xh (per-projection input; after attn: ctx)
    //   [+32MB, +64MB)   Qp
    //   [+64MB, +96MB)   Kp (after attn: Wo slot)
    int*    flag    = (int*)d_ws;
    float*  biasbuf = (float*)((char*)d_ws + 256);
    bf16_t* Xh      = (bf16_t*)((char*)d_ws + 32768);
    bf16_t* Qp      = Xh + nTok;
    bf16_t* Kp      = Qp + nTok;
    bf16_t* ctx     = Xh;   // Xh dead after V projection
    bf16_t* Wop     = Kp;   // Kp dead after attention

    // d_out (64 MB) doubles as scratch until the final GEMM owns it:
    //   lo 2MB: W slot for the three projections ; hi 32MB: Vp
    bf16_t* Wlo = (bf16_t*)d_out;
    bf16_t* Vp  = (bf16_t*)d_out + nTok;

    detect_and_bias<<<1, 256, 0, stream>>>((const unsigned short*)query, flag,
                                           bq, bk, bv, bo, biasbuf);

    cvt_w<<<1024, 256, 0, stream>>>(Wq, Wlo, flag);
    cvt_x<<<16384, 256, 0, stream>>>(query, Xh, flag);
    gemm8<<<256, 512, 0, stream>>>(Xh, Wlo, biasbuf + 0, Qp, flag, 0);

    cvt_w<<<1024, 256, 0, stream>>>(Wk, Wlo, flag);
    cvt_x<<<16384, 256, 0, stream>>>(key_, Xh, flag);
    gemm8<<<256, 512, 0, stream>>>(Xh, Wlo, biasbuf + 1024, Kp, flag, 0);

    cvt_w<<<1024, 256, 0, stream>>>(Wv, Wlo, flag);
    cvt_x<<<16384, 256, 0, stream>>>(value, Xh, flag);
    gemm8<<<256, 512, 0, stream>>>(Xh, Wlo, biasbuf + 2048, Vp, flag, 0);

    attn_local<<<dim3(NW, HH, DB), 256, 0, stream>>>(Qp, Kp, Vp, ctx);
    attn_global<<<dim3(HH, DB), 256, 0, stream>>>(Qp, Kp, Vp, gidx, ctx);

    cvt_w<<<1024, 256, 0, stream>>>(Wo, Wop, flag);
    gemm8<<<256, 512, 0, stream>>>(ctx, Wop, biasbuf + 3072, d_out, flag, 1);
}